// Round 21
// baseline (216.028 us; speedup 1.0000x reference)
//
#include <hip/hip_runtime.h>
#include <hip/hip_bf16.h>

using bf16 = __hip_bfloat16;
typedef __attribute__((ext_vector_type(8))) short short8;
typedef __attribute__((ext_vector_type(4))) short short4v;
typedef __attribute__((ext_vector_type(4))) float f32x4;
typedef __attribute__((ext_vector_type(4))) unsigned int u32x4;

__device__ __forceinline__ float b2f(bf16 x){ return __bfloat162float(x); }
__device__ __forceinline__ bf16  f2b(float x){ return __float2bfloat16(x); }
__device__ __forceinline__ float e2(float x){ return __builtin_amdgcn_exp2f(x); }
__device__ __forceinline__ unsigned pk2(float lo, float hi){
  return (unsigned)__bfloat16_as_ushort(f2b(lo)) | ((unsigned)__bfloat16_as_ushort(f2b(hi))<<16);
}
__device__ __forceinline__ float us2f(unsigned short u){
  unsigned v = (unsigned)u << 16; return __builtin_bit_cast(float, v);
}

__device__ __forceinline__ void gload_lds16(const void* g, void* l){
  __builtin_amdgcn_global_load_lds((const __attribute__((address_space(1))) unsigned int*)g,
                                   (__attribute__((address_space(3))) unsigned int*)l, 16, 0, 0);
}

// ---------------- merged weight transposes: f32 [R,C] -> bf16 [C,R], 12288 tiles ----------------
__global__ __launch_bounds__(256) void transpose_all(const float* __restrict__ wq, const float* __restrict__ wk,
                                                     const float* __restrict__ wv, const float* __restrict__ wo,
                                                     const float* __restrict__ w1, const float* __restrict__ w2,
                                                     bf16* __restrict__ wqkvT, bf16* __restrict__ woT,
                                                     bf16* __restrict__ w1T, bf16* __restrict__ w2T){
  __shared__ bf16 tile[32][33];
  int bid = blockIdx.x;
  const float* src; bf16* dst; int R, C, bx, by;
  if (bid < 3072){
    int which = bid >> 10, tl = bid & 1023;
    src = which==0 ? wq : (which==1 ? wk : wv);
    dst = wqkvT + (size_t)which*1024*1024;
    R = 1024; C = 1024; bx = (tl & 31)*32; by = (tl >> 5)*32;
  } else if (bid < 4096){
    int tl = bid - 3072; src = wo; dst = woT;
    R = 1024; C = 1024; bx = (tl & 31)*32; by = (tl >> 5)*32;
  } else if (bid < 8192){
    int tl = bid - 4096; src = w1; dst = w1T;
    R = 1024; C = 4096; bx = (tl & 127)*32; by = (tl >> 7)*32;
  } else {
    int tl = bid - 8192; src = w2; dst = w2T;
    R = 4096; C = 1024; bx = (tl & 31)*32; by = (tl >> 5)*32;
  }
  int tx = threadIdx.x & 31, ty = threadIdx.x >> 5;
  #pragma unroll
  for (int i=0;i<32;i+=8) tile[ty+i][tx] = f2b(src[(size_t)(by+ty+i)*C + bx+tx]);
  __syncthreads();
  #pragma unroll
  for (int i=0;i<32;i+=8) dst[(size_t)(bx+ty+i)*R + by+tx] = tile[tx][ty+i];
}

// ---------------- V transpose: qkvV[b*2048+n][ld] (h*64+d cols) -> vT[(b*16+h)*64+d][2048] ----------------
__global__ __launch_bounds__(256) void vtrans_k(const bf16* __restrict__ in, bf16* __restrict__ out, int ld){
  __shared__ bf16 tile[32][33];
  int bh = blockIdx.z, b = bh>>4, h = bh&15;
  int bn = blockIdx.x*32, bd = blockIdx.y*32;
  int tx = threadIdx.x, ty = threadIdx.y;
  #pragma unroll
  for (int i=0;i<32;i+=8)
    tile[ty+i][tx] = in[(size_t)(b*2048 + bn+ty+i)*ld + h*64 + bd+tx];
  __syncthreads();
  #pragma unroll
  for (int i=0;i<32;i+=8)
    out[(size_t)(bh*64 + bd+ty+i)*2048 + bn+tx] = tile[tx][ty+i];
}

// ---------------- layernorm f32-in: row of 1024 -> bf16, block=256, vectorized ----------------
__global__ __launch_bounds__(256) void ln_f32(const float* __restrict__ in, const float* __restrict__ w,
                                              const float* __restrict__ b, bf16* __restrict__ out){
  int row = blockIdx.x, t = threadIdx.x;
  const float4 v = *(const float4*)(in + (size_t)row*1024 + t*4);
  float s  = v.x+v.y+v.z+v.w;
  float s2 = v.x*v.x+v.y*v.y+v.z*v.z+v.w*v.w;
  #pragma unroll
  for (int d=1; d<64; d<<=1){ s += __shfl_xor(s,d,64); s2 += __shfl_xor(s2,d,64); }
  __shared__ float sb[8];
  if ((t&63)==0){ sb[t>>6]=s; sb[4+(t>>6)]=s2; }
  __syncthreads();
  s = sb[0]+sb[1]+sb[2]+sb[3]; s2 = sb[4]+sb[5]+sb[6]+sb[7];
  float mu = s*(1.f/1024.f);
  float rs = rsqrtf(s2*(1.f/1024.f) - mu*mu + 1e-5f);
  float4 wv = *(const float4*)(w + t*4);
  float4 bv = *(const float4*)(b + t*4);
  short4v o;
  o[0] = (short)__bfloat16_as_ushort(f2b((v.x-mu)*rs*wv.x + bv.x));
  o[1] = (short)__bfloat16_as_ushort(f2b((v.y-mu)*rs*wv.y + bv.y));
  o[2] = (short)__bfloat16_as_ushort(f2b((v.z-mu)*rs*wv.z + bv.z));
  o[3] = (short)__bfloat16_as_ushort(f2b((v.w-mu)*rs*wv.w + bv.w));
  *(short4v*)(out + (size_t)row*1024 + t*4) = o;
}

// ---------------- layernorm bf16-in: row of 1024 -> bf16, block=256, vectorized ----------------
__global__ __launch_bounds__(256) void ln_b16(const bf16* __restrict__ in, const float* __restrict__ w,
                                              const float* __restrict__ b, bf16* __restrict__ out){
  int row = blockIdx.x, t = threadIdx.x;
  short4v iv = *(const short4v*)(in + (size_t)row*1024 + t*4);
  float x0 = us2f((unsigned short)iv[0]), x1 = us2f((unsigned short)iv[1]);
  float x2 = us2f((unsigned short)iv[2]), x3 = us2f((unsigned short)iv[3]);
  float s  = x0+x1+x2+x3;
  float s2 = x0*x0+x1*x1+x2*x2+x3*x3;
  #pragma unroll
  for (int d=1; d<64; d<<=1){ s += __shfl_xor(s,d,64); s2 += __shfl_xor(s2,d,64); }
  __shared__ float sb[8];
  if ((t&63)==0){ sb[t>>6]=s; sb[4+(t>>6)]=s2; }
  __syncthreads();
  s = sb[0]+sb[1]+sb[2]+sb[3]; s2 = sb[4]+sb[5]+sb[6]+sb[7];
  float mu = s*(1.f/1024.f);
  float rs = rsqrtf(s2*(1.f/1024.f) - mu*mu + 1e-5f);
  float4 wv = *(const float4*)(w + t*4);
  float4 bv = *(const float4*)(b + t*4);
  short4v o;
  o[0] = (short)__bfloat16_as_ushort(f2b((x0-mu)*rs*wv.x + bv.x));
  o[1] = (short)__bfloat16_as_ushort(f2b((x1-mu)*rs*wv.y + bv.y));
  o[2] = (short)__bfloat16_as_ushort(f2b((x2-mu)*rs*wv.z + bv.z));
  o[3] = (short)__bfloat16_as_ushort(f2b((x3-mu)*rs*wv.w + bv.w));
  *(short4v*)(out + (size_t)row*1024 + t*4) = o;
}

// ---------------- big GEMM v2: 256x256 tile, 4-phase interleave over BK=64 (2x BK32 slots), counted vmcnt ----------------
// EPI: 0 = bias, first 1024 cols scaled by SC2 (QKV, pre-scales Q) -> bf16 ; 1 = bias+GELU(tanh-form) -> bf16
template<int EPI>
__global__ __launch_bounds__(512,2) void gemm256(const bf16* __restrict__ A, const bf16* __restrict__ Bt,
                                                 const float* __restrict__ bias, bf16* __restrict__ Cp,
                                                 int M, int N, int K){
  extern __shared__ char lds[];
  const int t = threadIdx.x, lane = t & 63, w = t >> 6;
  const int wm = w >> 2, wn = w & 3;
  const int lrow = lane & 15, g = lane >> 4;
  const int sw = (lrow & 7) << 4;

  const int nwg = gridDim.x;
  int flat = blockIdx.x;
  int nb = (nwg & 7) ? flat : ((flat & 7)*(nwg>>3) + (flat>>3));
  const int nbx = N >> 8;
  const int bm = (nb / nbx) << 8, bn = (nb % nbx) << 8;

  f32x4 acc[8][4] = {};
  const int nit = K >> 6;

  int srcOff[2];
  #pragma unroll
  for (int i=0;i<2;++i){
    int p = t + i*512;
    int r = ((p>>3)<<1) | (((p>>2)&1) ^ ((p>>4)&1));
    int gc = ((((p>>1)&1) ^ ((p>>3)&1))<<1) | ((p&1) ^ ((p>>2)&1) ^ ((p>>4)&1));
    srcOff[i] = r*K + gc*8;
  }

  auto STAGE_A = [&](int tt){
    char* sA = lds + (size_t)(tt&3)*32768;
    int k0 = tt << 5;
    #pragma unroll
    for (int i=0;i<2;++i)
      gload_lds16(A + (size_t)bm*K + srcOff[i] + k0, sA + (unsigned)(i*8192 + w*1024));
  };
  auto STAGE_B = [&](int tt){
    char* sB = lds + (size_t)(tt&3)*32768 + 16384;
    int k0 = tt << 5;
    #pragma unroll
    for (int i=0;i<2;++i)
      gload_lds16(Bt + (size_t)bn*K + srcOff[i] + k0, sB + (unsigned)(i*8192 + w*1024));
  };

  auto RD_A = [&](int tt, int mh, short8* af){
    const char* sA = lds + (size_t)(tt&3)*32768;
    #pragma unroll
    for (int mf=0;mf<4;++mf)
      af[mf] = *(const short8*)(sA + (((wm*128 + (mh*4+mf)*16 + lrow)*64 + g*16) ^ sw));
  };
  auto RD_B = [&](int tt, short8* bfr){
    const char* sB = lds + (size_t)(tt&3)*32768 + 16384;
    #pragma unroll
    for (int nf=0;nf<4;++nf)
      bfr[nf] = *(const short8*)(sB + (((wn*64 + nf*16 + lrow)*64 + g*16) ^ sw));
  };
  auto MM = [&](short8* af, short8* bfr, int mh){
    __builtin_amdgcn_s_setprio(1);
    #pragma unroll
    for (int mf=0;mf<4;++mf)
      #pragma unroll
      for (int nf=0;nf<4;++nf)
        acc[mh*4+mf][nf] = __builtin_amdgcn_mfma_f32_16x16x32_bf16(af[mf], bfr[nf], acc[mh*4+mf][nf], 0,0,0);
    __builtin_amdgcn_s_setprio(0);
  };

  STAGE_A(0); STAGE_B(0); STAGE_A(1); STAGE_B(1);
  asm volatile("s_waitcnt vmcnt(4)" ::: "memory");
  __builtin_amdgcn_s_barrier();

  for (int T=0; T<nit; ++T){
    int u = 2*T, v = u+1;
    bool st = (T+1 < nit);
    short8 af[4], bfr[4];

    RD_B(u, bfr); RD_A(u, 0, af);
    if (st) STAGE_A(u+2);
    __builtin_amdgcn_s_barrier();
    MM(af, bfr, 0);

    RD_A(u, 1, af);
    if (st) STAGE_B(u+2);
    __builtin_amdgcn_s_barrier();
    MM(af, bfr, 1);
    if (st) asm volatile("s_waitcnt vmcnt(4)" ::: "memory");
    else    asm volatile("s_waitcnt vmcnt(0)" ::: "memory");
    __builtin_amdgcn_s_barrier();

    RD_B(v, bfr); RD_A(v, 0, af);
    if (st) STAGE_A(v+2);
    __builtin_amdgcn_s_barrier();
    MM(af, bfr, 0);

    RD_A(v, 1, af);
    if (st) STAGE_B(v+2);
    __builtin_amdgcn_s_barrier();
    MM(af, bfr, 1);
    if (st) asm volatile("s_waitcnt vmcnt(4)" ::: "memory");
    __builtin_amdgcn_s_barrier();
  }

  const float SC2 = 0.125f * 1.44269504089f;
  #pragma unroll
  for (int mf=0;mf<8;++mf){
    int rowb = bm + wm*128 + mf*16 + g*4;
    #pragma unroll
    for (int nf=0;nf<4;++nf){
      int col = bn + wn*64 + nf*16 + lrow;
      float bv = bias[col];
      #pragma unroll
      for (int r=0;r<4;++r){
        float vv = acc[mf][nf][r] + bv;
        if constexpr (EPI==0){ if (col < 1024) vv *= SC2; }
        if constexpr (EPI==1){
          float ex = e2(-2.3022080654f*(vv + 0.044715f*vv*vv*vv));
          vv = vv * __builtin_amdgcn_rcpf(1.0f + ex);
        }
        Cp[(size_t)(rowb+r)*N + col] = f2b(vv);
      }
    }
  }
}

// ---------------- mid GEMM v3: 128x128 tile, BK=64, 8 waves, 4-deep ring (128KB), counted vmcnt ----------------
// EPI: 3 = bias + f32 residual -> bf16 out ; 4 = bias + bf16 residual -> f32 out
template<int EPI>
__global__ __launch_bounds__(512,1) void gemm128(const bf16* __restrict__ A, const bf16* __restrict__ Bt,
                                                 const float* __restrict__ bias, const void* __restrict__ res,
                                                 void* __restrict__ Cp, int M, int N, int K){
  extern __shared__ char lds[];
  const int t = threadIdx.x, lane = t & 63, w = t >> 6;
  const int wm = w >> 2, wn = w & 3;
  const int lrow = lane & 15, g = lane >> 4;
  const int sw = (lrow & 7) << 4;

  const int nwg = gridDim.x;
  int flat = blockIdx.x;
  int nb = (nwg & 7) ? flat : ((flat & 7)*(nwg>>3) + (flat>>3));
  const int nbx = N >> 7;
  const int bm = (nb / nbx) << 7, bn = (nb % nbx) << 7;

  f32x4 acc[4][2] = {};
  const int nt = K >> 6;

  int srcOff[2];
  #pragma unroll
  for (int i=0;i<2;++i){
    int p = t + i*512;
    int r = p >> 3;
    int sl = (p & 7) ^ (r & 7);
    srcOff[i] = r*K + sl*8;
  }

  auto STAGE = [&](int tt){
    char* sA = lds + (size_t)(tt&3)*32768;
    char* sB = sA + 16384;
    int k0 = tt << 6;
    #pragma unroll
    for (int i=0;i<2;++i){
      unsigned dst = (unsigned)(i*8192 + w*1024);
      gload_lds16(A  + (size_t)bm*K + srcOff[i] + k0, sA + dst);
      gload_lds16(Bt + (size_t)bn*K + srcOff[i] + k0, sB + dst);
    }
  };

  auto COMPUTE = [&](int tt){
    const char* sA = lds + (size_t)(tt&3)*32768;
    const char* sB = sA + 16384;
    #pragma unroll
    for (int ks=0; ks<2; ++ks){
      short8 af[4], bfr[2];
      #pragma unroll
      for (int mf=0;mf<4;++mf)
        af[mf] = *(const short8*)(sA + (((wm*64 + mf*16 + lrow)*128 + ks*64 + g*16) ^ sw));
      #pragma unroll
      for (int nf=0;nf<2;++nf)
        bfr[nf] = *(const short8*)(sB + (((wn*32 + nf*16 + lrow)*128 + ks*64 + g*16) ^ sw));
      __builtin_amdgcn_s_setprio(1);
      #pragma unroll
      for (int mf=0;mf<4;++mf)
        #pragma unroll
        for (int nf=0;nf<2;++nf)
          acc[mf][nf] = __builtin_amdgcn_mfma_f32_16x16x32_bf16(af[mf], bfr[nf], acc[mf][nf], 0,0,0);
      __builtin_amdgcn_s_setprio(0);
    }
  };

  STAGE(0); STAGE(1); STAGE(2);
  asm volatile("s_waitcnt vmcnt(8)" ::: "memory");
  __builtin_amdgcn_s_barrier();

  for (int tt=0; tt<nt-3; ++tt){
    STAGE(tt+3);
    COMPUTE(tt);
    asm volatile("s_waitcnt vmcnt(8)" ::: "memory");
    __builtin_amdgcn_s_barrier();
  }
  COMPUTE(nt-3);
  asm volatile("s_waitcnt vmcnt(4)" ::: "memory");
  __builtin_amdgcn_s_barrier();
  COMPUTE(nt-2);
  asm volatile("s_waitcnt vmcnt(0)" ::: "memory");
  __builtin_amdgcn_s_barrier();
  COMPUTE(nt-1);

  #pragma unroll
  for (int mf=0;mf<4;++mf){
    int rowb = bm + wm*64 + mf*16 + g*4;
    #pragma unroll
    for (int nf=0;nf<2;++nf){
      int col = bn + wn*32 + nf*16 + lrow;
      float bv = bias[col];
      #pragma unroll
      for (int r=0;r<4;++r){
        size_t idx = (size_t)(rowb+r)*N + col;
        float vv = acc[mf][nf][r] + bv;
        if constexpr (EPI==3){ vv += ((const float*)res)[idx]; ((bf16*)Cp)[idx] = f2b(vv); }
        else { vv += b2f(((const bf16*)res)[idx]); ((float*)Cp)[idx] = vv; }
      }
    }
  }
}

// ---------------- flash attention v11: 3-slot ring (48KB -> 3 blocks/CU), counted vmcnt ----------------
// q pre-scaled by 0.125*log2e. Static softmax; in-reg P exchange. Stage distance 2; ledger vmcnt(2)/(0).
__global__ __launch_bounds__(512,6) void attn_k(const bf16* __restrict__ q, const bf16* __restrict__ k,
                                                const bf16* __restrict__ vT, bf16* __restrict__ o, int ldq){
  __shared__ char KV[3][16384];   // [slot][K 8KB | V 8KB]

  int flat = blockIdx.x;
  int xs = flat & 7, j = flat >> 3;
  int bh = xs*4 + (j & 3), qt = j >> 2;
  int b = bh >> 4, h = bh & 15;
  int t = threadIdx.x, lane = t & 63, w = t >> 6;
  int lrow = lane & 15, g = lane >> 4, lko = g*8;

  const bf16* kbase = k  + (size_t)b*2048*ldq + h*64;
  const bf16* vtb   = vT + (size_t)bh*64*2048;

  size_t qrow = (size_t)(b*2048 + qt*128 + w*16 + lrow);
  short8 qf0 = *(const short8*)(q + qrow*ldq + h*64 + lko);
  short8 qf1 = *(const short8*)(q + qrow*ldq + h*64 + 32 + lko);

  int srow = t >> 3, scolb = (t & 7) << 4;
  int ssw = scolb ^ ((srow & 7) << 4);
  const bf16* ksrc = kbase + (size_t)srow*ldq + (ssw >> 1);
  const bf16* vsrc = vtb   + (size_t)srow*2048 + (ssw >> 1);
  unsigned ldst = (unsigned)(w*1024);

  const short8 onesf = {0x3F80,0x3F80,0x3F80,0x3F80,0x3F80,0x3F80,0x3F80,0x3F80};

  const int srcU = lrow + ((2*(g&1) + (g>>1)) << 4);
  const int srcV = lrow + ((2*(g&1) + 1 - (g>>1)) << 4);
  const bool gOdd = (g & 1), lo = ((g>>1) == 0);

  f32x4 lacc = {};
  f32x4 oacc[4] = {};
  const int sw = (lrow & 7) << 4;

  auto STAGE = [&](int tile){
    char* s = KV[tile % 3];
    int kt = tile * 64;
    gload_lds16(ksrc + (size_t)kt*ldq, s + ldst);
    gload_lds16(vsrc + kt,             s + 8192 + ldst);
  };

  auto BODY = [&](int tile){
    const char* Kc = KV[tile % 3];
    const char* Vc = Kc + 8192;

    f32x4 s[4];
    __builtin_amdgcn_s_setprio(1);
    #pragma unroll
    for (int cb=0; cb<4; ++cb){
      const char* kp = Kc + (cb*16 + lrow)*128;
      short8 kf0 = *(const short8*)(kp + ((g*16) ^ sw));
      short8 kf1 = *(const short8*)(kp + ((64 + g*16) ^ sw));
      f32x4 a = {};
      a = __builtin_amdgcn_mfma_f32_16x16x32_bf16(kf0, qf0, a, 0,0,0);
      a = __builtin_amdgcn_mfma_f32_16x16x32_bf16(kf1, qf1, a, 0,0,0);
      s[cb] = a;
    }
    __builtin_amdgcn_s_setprio(0);

    unsigned pA0 = pk2(e2(s[0][0]), e2(s[0][1]));
    unsigned pB0 = pk2(e2(s[0][2]), e2(s[0][3]));
    unsigned pA1 = pk2(e2(s[1][0]), e2(s[1][1]));
    unsigned pB1 = pk2(e2(s[1][2]), e2(s[1][3]));
    unsigned pA2 = pk2(e2(s[2][0]), e2(s[2][1]));
    unsigned pB2 = pk2(e2(s[2][2]), e2(s[2][3]));
    unsigned pA3 = pk2(e2(s[3][0]), e2(s[3][1]));
    unsigned pB3 = pk2(e2(s[3][2]), e2(s[3][3]));

    unsigned ruA = __shfl((int)(gOdd?pA1:pA0), srcU, 64);
    unsigned rvA = __shfl((int)(gOdd?pA0:pA1), srcV, 64);
    unsigned ruB = __shfl((int)(gOdd?pB1:pB0), srcU, 64);
    unsigned rvB = __shfl((int)(gOdd?pB0:pB1), srcV, 64);
    unsigned ruA2= __shfl((int)(gOdd?pA3:pA2), srcU, 64);
    unsigned rvA2= __shfl((int)(gOdd?pA2:pA3), srcV, 64);
    unsigned ruB2= __shfl((int)(gOdd?pB3:pB2), srcU, 64);
    unsigned rvB2= __shfl((int)(gOdd?pB2:pB3), srcV, 64);

    u32x4 w0 = { lo?ruA:rvA,  lo?ruB:rvB,  lo?rvA:ruA,  lo?rvB:ruB  };
    u32x4 w1 = { lo?ruA2:rvA2,lo?ruB2:rvB2,lo?rvA2:ruA2,lo?rvB2:ruB2};
    short8 pf0 = __builtin_bit_cast(short8, w0);
    short8 pf1 = __builtin_bit_cast(short8, w1);

    __builtin_amdgcn_s_setprio(1);
    lacc = __builtin_amdgcn_mfma_f32_16x16x32_bf16(pf0, onesf, lacc, 0,0,0);
    lacc = __builtin_amdgcn_mfma_f32_16x16x32_bf16(pf1, onesf, lacc, 0,0,0);
    #pragma unroll
    for (int half=0; half<2; ++half){
      short8 pf = half ? pf1 : pf0;
      #pragma unroll
      for (int db=0; db<4; ++db){
        const char* vp = Vc + (db*16 + lrow)*128;
        short8 vf = *(const short8*)(vp + ((half*64 + g*16) ^ sw));
        oacc[db] = __builtin_amdgcn_mfma_f32_16x16x32_bf16(pf, vf, oacc[db], 0,0,0);
      }
    }
    __builtin_amdgcn_s_setprio(0);
  };

  STAGE(0); STAGE(1);
  asm volatile("s_waitcnt vmcnt(2)" ::: "memory");
  __builtin_amdgcn_s_barrier();

  for (int tile = 0; tile < 30; ++tile){
    STAGE(tile+2);
    BODY(tile);
    asm volatile("s_waitcnt vmcnt(2)" ::: "memory");
    __builtin_amdgcn_s_barrier();
  }
  BODY(30);
  asm volatile("s_waitcnt vmcnt(0)" ::: "memory");
  __builtin_amdgcn_s_barrier();
  BODY(31);

  f32x4 inv;
  #pragma unroll
  for (int r=0;r<4;++r) inv[r] = 1.0f/lacc[r];
  size_t obase = ((size_t)(b*2048 + qt*128 + w*16))*1024 + h*64;
  #pragma unroll
  for (int db=0; db<4; ++db)
    #pragma unroll
    for (int r=0;r<4;++r)
      o[obase + (size_t)(g*4+r)*1024 + db*16 + lrow] = f2b(oacc[db][r] * inv[r]);
}

// ---------------- launch ----------------
extern "C" void kernel_launch(void* const* d_in, const int* in_sizes, int n_in,
                              void* d_out, int out_size, void* d_ws, size_t ws_size,
                              hipStream_t stream) {
  (void)in_sizes; (void)n_in; (void)out_size; (void)ws_size;
  const float* x    = (const float*)d_in[0];
  const float* ln1w = (const float*)d_in[1];
  const float* ln1b = (const float*)d_in[2];
  const float* ln2w = (const float*)d_in[3];
  const float* ln2b = (const float*)d_in[4];
  const float* wq   = (const float*)d_in[5];
  const float* bq   = (const float*)d_in[6];
  const float* wk   = (const float*)d_in[7];
  const float* bk   = (const float*)d_in[8];
  const float* wv   = (const float*)d_in[9];
  const float* bv   = (const float*)d_in[10];
  const float* wo   = (const float*)d_in[11];
  const float* bo   = (const float*)d_in[12];
  const float* w1   = (const float*)d_in[13];
  const float* b1   = (const float*)d_in[14];
  const float* w2   = (const float*)d_in[15];
  const float* b2   = (const float*)d_in[16];

  char* ws = (char*)d_ws;
  const size_t MB = 1u<<20;
  bf16* wqkvT = (bf16*)(ws + 0*MB);   // [3072,1024] bf16
  bf16* woT   = (bf16*)(ws + 6*MB);
  bf16* w1T   = (bf16*)(ws + 8*MB);   // [4096,1024]
  bf16* w2T   = (bf16*)(ws + 16*MB);  // [1024,4096]
  bf16* qkv   = (bf16*)(ws + 24*MB);  // [4096,3072] bf16 = 24 MB
  bf16* ao    = (bf16*)(ws + 48*MB);  // [4096,1024] bf16 = 8 MB
  bf16* vT    = (bf16*)(ws + 56*MB);  // 8 MB, alive only during attn
  bf16* x1b   = (bf16*)(ws + 64*MB);  // [4096,1024] bf16 residual = 8 MB
  bf16* lnb   = (bf16*)(ws + 72*MB);  // 8 MB
  bf16* h1    = (bf16*)(ws + 24*MB);  // [4096,4096] bf16 = 32 MB, reuse qkv+ao after proj
  float* bqkv = (float*)(ws + 80*MB); // 12 KB

  hipMemcpyAsync(bqkv,        bq, 1024*sizeof(float), hipMemcpyDeviceToDevice, stream);
  hipMemcpyAsync(bqkv + 1024, bk, 1024*sizeof(float), hipMemcpyDeviceToDevice, stream);
  hipMemcpyAsync(bqkv + 2048, bv, 1024*sizeof(float), hipMemcpyDeviceToDevice, stream);

  transpose_all<<<12288,256,0,stream>>>(wq, wk, wv, wo, w1, w2, wqkvT, woT, w1T, w2T);

  ln_f32<<<4096,256,0,stream>>>(x, ln1w, ln1b, lnb);
  gemm256<0><<<192,512,131072,stream>>>(lnb, wqkvT, bqkv, qkv, 4096,3072,1024);
  vtrans_k<<<dim3(64,2,32),dim3(32,8),0,stream>>>(qkv + 2048, vT, 3072);
  attn_k<<<512,512,0,stream>>>(qkv, qkv + 1024, vT, ao, 3072);
  gemm128<3><<<256,512,131072,stream>>>(ao, woT, bo, x, x1b, 4096,1024,1024);
  ln_b16<<<4096,256,0,stream>>>(x1b, ln2w, ln2b, lnb);
  gemm256<1><<<256,512,131072,stream>>>(lnb, w1T, b1, h1, 4096,4096,1024);
  gemm128<4><<<256,512,131072,stream>>>(h1, w2T, b2, x1b, (float*)d_out, 4096,1024,4096);
}

// Round 22
// 213.960 us; speedup vs baseline: 1.0097x; 1.0097x over previous
//
#include <hip/hip_runtime.h>
#include <hip/hip_bf16.h>

using bf16 = __hip_bfloat16;
typedef __attribute__((ext_vector_type(8))) short short8;
typedef __attribute__((ext_vector_type(4))) short short4v;
typedef __attribute__((ext_vector_type(4))) float f32x4;
typedef __attribute__((ext_vector_type(2))) unsigned int u32x2;
typedef __attribute__((ext_vector_type(4))) unsigned int u32x4;

__device__ __forceinline__ float b2f(bf16 x){ return __bfloat162float(x); }
__device__ __forceinline__ bf16  f2b(float x){ return __float2bfloat16(x); }
__device__ __forceinline__ float e2(float x){ return __builtin_amdgcn_exp2f(x); }
__device__ __forceinline__ unsigned pk2(float lo, float hi){
  return (unsigned)__bfloat16_as_ushort(f2b(lo)) | ((unsigned)__bfloat16_as_ushort(f2b(hi))<<16);
}
__device__ __forceinline__ float us2f(unsigned short u){
  unsigned v = (unsigned)u << 16; return __builtin_bit_cast(float, v);
}

__device__ __forceinline__ void gload_lds16(const void* g, void* l){
  __builtin_amdgcn_global_load_lds((const __attribute__((address_space(1))) unsigned int*)g,
                                   (__attribute__((address_space(3))) unsigned int*)l, 16, 0, 0);
}

// ---------------- merged weight transposes: f32 [R,C] -> bf16 [C,R], 12288 tiles ----------------
__global__ __launch_bounds__(256) void transpose_all(const float* __restrict__ wq, const float* __restrict__ wk,
                                                     const float* __restrict__ wv, const float* __restrict__ wo,
                                                     const float* __restrict__ w1, const float* __restrict__ w2,
                                                     bf16* __restrict__ wqkvT, bf16* __restrict__ woT,
                                                     bf16* __restrict__ w1T, bf16* __restrict__ w2T){
  __shared__ bf16 tile[32][33];
  int bid = blockIdx.x;
  const float* src; bf16* dst; int R, C, bx, by;
  if (bid < 3072){
    int which = bid >> 10, tl = bid & 1023;
    src = which==0 ? wq : (which==1 ? wk : wv);
    dst = wqkvT + (size_t)which*1024*1024;
    R = 1024; C = 1024; bx = (tl & 31)*32; by = (tl >> 5)*32;
  } else if (bid < 4096){
    int tl = bid - 3072; src = wo; dst = woT;
    R = 1024; C = 1024; bx = (tl & 31)*32; by = (tl >> 5)*32;
  } else if (bid < 8192){
    int tl = bid - 4096; src = w1; dst = w1T;
    R = 1024; C = 4096; bx = (tl & 127)*32; by = (tl >> 7)*32;
  } else {
    int tl = bid - 8192; src = w2; dst = w2T;
    R = 4096; C = 1024; bx = (tl & 31)*32; by = (tl >> 5)*32;
  }
  int tx = threadIdx.x & 31, ty = threadIdx.x >> 5;
  #pragma unroll
  for (int i=0;i<32;i+=8) tile[ty+i][tx] = f2b(src[(size_t)(by+ty+i)*C + bx+tx]);
  __syncthreads();
  #pragma unroll
  for (int i=0;i<32;i+=8) dst[(size_t)(bx+ty+i)*R + by+tx] = tile[tx][ty+i];
}

// ---------------- layernorm f32-in: row of 1024 -> bf16, block=256, vectorized ----------------
__global__ __launch_bounds__(256) void ln_f32(const float* __restrict__ in, const float* __restrict__ w,
                                              const float* __restrict__ b, bf16* __restrict__ out){
  int row = blockIdx.x, t = threadIdx.x;
  const float4 v = *(const float4*)(in + (size_t)row*1024 + t*4);
  float s  = v.x+v.y+v.z+v.w;
  float s2 = v.x*v.x+v.y*v.y+v.z*v.z+v.w*v.w;
  #pragma unroll
  for (int d=1; d<64; d<<=1){ s += __shfl_xor(s,d,64); s2 += __shfl_xor(s2,d,64); }
  __shared__ float sb[8];
  if ((t&63)==0){ sb[t>>6]=s; sb[4+(t>>6)]=s2; }
  __syncthreads();
  s = sb[0]+sb[1]+sb[2]+sb[3]; s2 = sb[4]+sb[5]+sb[6]+sb[7];
  float mu = s*(1.f/1024.f);
  float rs = rsqrtf(s2*(1.f/1024.f) - mu*mu + 1e-5f);
  float4 wv = *(const float4*)(w + t*4);
  float4 bv = *(const float4*)(b + t*4);
  short4v o;
  o[0] = (short)__bfloat16_as_ushort(f2b((v.x-mu)*rs*wv.x + bv.x));
  o[1] = (short)__bfloat16_as_ushort(f2b((v.y-mu)*rs*wv.y + bv.y));
  o[2] = (short)__bfloat16_as_ushort(f2b((v.z-mu)*rs*wv.z + bv.z));
  o[3] = (short)__bfloat16_as_ushort(f2b((v.w-mu)*rs*wv.w + bv.w));
  *(short4v*)(out + (size_t)row*1024 + t*4) = o;
}

// ---------------- layernorm bf16-in: row of 1024 -> bf16, block=256, vectorized ----------------
__global__ __launch_bounds__(256) void ln_b16(const bf16* __restrict__ in, const float* __restrict__ w,
                                              const float* __restrict__ b, bf16* __restrict__ out){
  int row = blockIdx.x, t = threadIdx.x;
  short4v iv = *(const short4v*)(in + (size_t)row*1024 + t*4);
  float x0 = us2f((unsigned short)iv[0]), x1 = us2f((unsigned short)iv[1]);
  float x2 = us2f((unsigned short)iv[2]), x3 = us2f((unsigned short)iv[3]);
  float s  = x0+x1+x2+x3;
  float s2 = x0*x0+x1*x1+x2*x2+x3*x3;
  #pragma unroll
  for (int d=1; d<64; d<<=1){ s += __shfl_xor(s,d,64); s2 += __shfl_xor(s2,d,64); }
  __shared__ float sb[8];
  if ((t&63)==0){ sb[t>>6]=s; sb[4+(t>>6)]=s2; }
  __syncthreads();
  s = sb[0]+sb[1]+sb[2]+sb[3]; s2 = sb[4]+sb[5]+sb[6]+sb[7];
  float mu = s*(1.f/1024.f);
  float rs = rsqrtf(s2*(1.f/1024.f) - mu*mu + 1e-5f);
  float4 wv = *(const float4*)(w + t*4);
  float4 bv = *(const float4*)(b + t*4);
  short4v o;
  o[0] = (short)__bfloat16_as_ushort(f2b((x0-mu)*rs*wv.x + bv.x));
  o[1] = (short)__bfloat16_as_ushort(f2b((x1-mu)*rs*wv.y + bv.y));
  o[2] = (short)__bfloat16_as_ushort(f2b((x2-mu)*rs*wv.z + bv.z));
  o[3] = (short)__bfloat16_as_ushort(f2b((x3-mu)*rs*wv.w + bv.w));
  *(short4v*)(out + (size_t)row*1024 + t*4) = o;
}

// ---------------- big GEMM v2: 256x256 tile, 4-phase interleave over BK=64 (2x BK32 slots), counted vmcnt ----------------
// EPI: 0 = QKV (Q cols pre-scaled by SC2; V cols written TRANSPOSED to Vout) ; 1 = bias+GELU(tanh-form)
template<int EPI>
__global__ __launch_bounds__(512,2) void gemm256(const bf16* __restrict__ A, const bf16* __restrict__ Bt,
                                                 const float* __restrict__ bias, bf16* __restrict__ Cp,
                                                 bf16* __restrict__ Vout, int M, int N, int K){
  extern __shared__ char lds[];
  const int t = threadIdx.x, lane = t & 63, w = t >> 6;
  const int wm = w >> 2, wn = w & 3;
  const int lrow = lane & 15, g = lane >> 4;
  const int sw = (lrow & 7) << 4;

  const int nwg = gridDim.x;
  int flat = blockIdx.x;
  int nb = (nwg & 7) ? flat : ((flat & 7)*(nwg>>3) + (flat>>3));
  const int nbx = N >> 8;
  const int bm = (nb / nbx) << 8, bn = (nb % nbx) << 8;

  f32x4 acc[8][4] = {};
  const int nit = K >> 6;

  int srcOff[2];
  #pragma unroll
  for (int i=0;i<2;++i){
    int p = t + i*512;
    int r = ((p>>3)<<1) | (((p>>2)&1) ^ ((p>>4)&1));
    int gc = ((((p>>1)&1) ^ ((p>>3)&1))<<1) | ((p&1) ^ ((p>>2)&1) ^ ((p>>4)&1));
    srcOff[i] = r*K + gc*8;
  }

  auto STAGE_A = [&](int tt){
    char* sA = lds + (size_t)(tt&3)*32768;
    int k0 = tt << 5;
    #pragma unroll
    for (int i=0;i<2;++i)
      gload_lds16(A + (size_t)bm*K + srcOff[i] + k0, sA + (unsigned)(i*8192 + w*1024));
  };
  auto STAGE_B = [&](int tt){
    char* sB = lds + (size_t)(tt&3)*32768 + 16384;
    int k0 = tt << 5;
    #pragma unroll
    for (int i=0;i<2;++i)
      gload_lds16(Bt + (size_t)bn*K + srcOff[i] + k0, sB + (unsigned)(i*8192 + w*1024));
  };

  auto RD_A = [&](int tt, int mh, short8* af){
    const char* sA = lds + (size_t)(tt&3)*32768;
    #pragma unroll
    for (int mf=0;mf<4;++mf)
      af[mf] = *(const short8*)(sA + (((wm*128 + (mh*4+mf)*16 + lrow)*64 + g*16) ^ sw));
  };
  auto RD_B = [&](int tt, short8* bfr){
    const char* sB = lds + (size_t)(tt&3)*32768 + 16384;
    #pragma unroll
    for (int nf=0;nf<4;++nf)
      bfr[nf] = *(const short8*)(sB + (((wn*64 + nf*16 + lrow)*64 + g*16) ^ sw));
  };
  auto MM = [&](short8* af, short8* bfr, int mh){
    __builtin_amdgcn_s_setprio(1);
    #pragma unroll
    for (int mf=0;mf<4;++mf)
      #pragma unroll
      for (int nf=0;nf<4;++nf)
        acc[mh*4+mf][nf] = __builtin_amdgcn_mfma_f32_16x16x32_bf16(af[mf], bfr[nf], acc[mh*4+mf][nf], 0,0,0);
    __builtin_amdgcn_s_setprio(0);
  };

  STAGE_A(0); STAGE_B(0); STAGE_A(1); STAGE_B(1);
  asm volatile("s_waitcnt vmcnt(4)" ::: "memory");
  __builtin_amdgcn_s_barrier();

  for (int T=0; T<nit; ++T){
    int u = 2*T, v = u+1;
    bool st = (T+1 < nit);
    short8 af[4], bfr[4];

    RD_B(u, bfr); RD_A(u, 0, af);
    if (st) STAGE_A(u+2);
    __builtin_amdgcn_s_barrier();
    MM(af, bfr, 0);

    RD_A(u, 1, af);
    if (st) STAGE_B(u+2);
    __builtin_amdgcn_s_barrier();
    MM(af, bfr, 1);
    if (st) asm volatile("s_waitcnt vmcnt(4)" ::: "memory");
    else    asm volatile("s_waitcnt vmcnt(0)" ::: "memory");
    __builtin_amdgcn_s_barrier();

    RD_B(v, bfr); RD_A(v, 0, af);
    if (st) STAGE_A(v+2);
    __builtin_amdgcn_s_barrier();
    MM(af, bfr, 0);

    RD_A(v, 1, af);
    if (st) STAGE_B(v+2);
    __builtin_amdgcn_s_barrier();
    MM(af, bfr, 1);
    if (st) asm volatile("s_waitcnt vmcnt(4)" ::: "memory");
    __builtin_amdgcn_s_barrier();
  }

  const float SC2 = 0.125f * 1.44269504089f;
  #pragma unroll
  for (int mf=0;mf<8;++mf){
    int rowb = bm + wm*128 + mf*16 + g*4;
    #pragma unroll
    for (int nf=0;nf<4;++nf){
      int col = bn + wn*64 + nf*16 + lrow;
      float bv = bias[col];
      if constexpr (EPI==0){
        if (col >= 2048){
          // V column: write transposed to Vout[(b*1024 + h*64 + d)][n], packed 4 consecutive n
          size_t vrow = (size_t)((rowb >> 11)*1024 + (col - 2048));
          u32x2 pkv;
          pkv[0] = pk2(acc[mf][nf][0] + bv, acc[mf][nf][1] + bv);
          pkv[1] = pk2(acc[mf][nf][2] + bv, acc[mf][nf][3] + bv);
          *(u32x2*)(Vout + vrow*2048 + (rowb & 2047)) = pkv;
        } else {
          float sc = (col < 1024) ? SC2 : 1.0f;
          #pragma unroll
          for (int r=0;r<4;++r)
            Cp[(size_t)(rowb+r)*N + col] = f2b((acc[mf][nf][r] + bv) * sc);
        }
      } else {
        #pragma unroll
        for (int r=0;r<4;++r){
          float vv = acc[mf][nf][r] + bv;
          float ex = e2(-2.3022080654f*(vv + 0.044715f*vv*vv*vv));
          vv = vv * __builtin_amdgcn_rcpf(1.0f + ex);
          Cp[(size_t)(rowb+r)*N + col] = f2b(vv);
        }
      }
    }
  }
}

// ---------------- mid GEMM v3: 128x128 tile, BK=64, 8 waves, 4-deep ring (128KB), counted vmcnt ----------------
// EPI: 3 = bias + f32 residual -> bf16 out ; 4 = bias + bf16 residual -> f32 out
template<int EPI>
__global__ __launch_bounds__(512,1) void gemm128(const bf16* __restrict__ A, const bf16* __restrict__ Bt,
                                                 const float* __restrict__ bias, const void* __restrict__ res,
                                                 void* __restrict__ Cp, int M, int N, int K){
  extern __shared__ char lds[];
  const int t = threadIdx.x, lane = t & 63, w = t >> 6;
  const int wm = w >> 2, wn = w & 3;
  const int lrow = lane & 15, g = lane >> 4;
  const int sw = (lrow & 7) << 4;

  const int nwg = gridDim.x;
  int flat = blockIdx.x;
  int nb = (nwg & 7) ? flat : ((flat & 7)*(nwg>>3) + (flat>>3));
  const int nbx = N >> 7;
  const int bm = (nb / nbx) << 7, bn = (nb % nbx) << 7;

  f32x4 acc[4][2] = {};
  const int nt = K >> 6;

  int srcOff[2];
  #pragma unroll
  for (int i=0;i<2;++i){
    int p = t + i*512;
    int r = p >> 3;
    int sl = (p & 7) ^ (r & 7);
    srcOff[i] = r*K + sl*8;
  }

  auto STAGE = [&](int tt){
    char* sA = lds + (size_t)(tt&3)*32768;
    char* sB = sA + 16384;
    int k0 = tt << 6;
    #pragma unroll
    for (int i=0;i<2;++i){
      unsigned dst = (unsigned)(i*8192 + w*1024);
      gload_lds16(A  + (size_t)bm*K + srcOff[i] + k0, sA + dst);
      gload_lds16(Bt + (size_t)bn*K + srcOff[i] + k0, sB + dst);
    }
  };

  auto COMPUTE = [&](int tt){
    const char* sA = lds + (size_t)(tt&3)*32768;
    const char* sB = sA + 16384;
    #pragma unroll
    for (int ks=0; ks<2; ++ks){
      short8 af[4], bfr[2];
      #pragma unroll
      for (int mf=0;mf<4;++mf)
        af[mf] = *(const short8*)(sA + (((wm*64 + mf*16 + lrow)*128 + ks*64 + g*16) ^ sw));
      #pragma unroll
      for (int nf=0;nf<2;++nf)
        bfr[nf] = *(const short8*)(sB + (((wn*32 + nf*16 + lrow)*128 + ks*64 + g*16) ^ sw));
      __builtin_amdgcn_s_setprio(1);
      #pragma unroll
      for (int mf=0;mf<4;++mf)
        #pragma unroll
        for (int nf=0;nf<2;++nf)
          acc[mf][nf] = __builtin_amdgcn_mfma_f32_16x16x32_bf16(af[mf], bfr[nf], acc[mf][nf], 0,0,0);
      __builtin_amdgcn_s_setprio(0);
    }
  };

  STAGE(0); STAGE(1); STAGE(2);
  asm volatile("s_waitcnt vmcnt(8)" ::: "memory");
  __builtin_amdgcn_s_barrier();

  for (int tt=0; tt<nt-3; ++tt){
    STAGE(tt+3);
    COMPUTE(tt);
    asm volatile("s_waitcnt vmcnt(8)" ::: "memory");
    __builtin_amdgcn_s_barrier();
  }
  COMPUTE(nt-3);
  asm volatile("s_waitcnt vmcnt(4)" ::: "memory");
  __builtin_amdgcn_s_barrier();
  COMPUTE(nt-2);
  asm volatile("s_waitcnt vmcnt(0)" ::: "memory");
  __builtin_amdgcn_s_barrier();
  COMPUTE(nt-1);

  #pragma unroll
  for (int mf=0;mf<4;++mf){
    int rowb = bm + wm*64 + mf*16 + g*4;
    #pragma unroll
    for (int nf=0;nf<2;++nf){
      int col = bn + wn*32 + nf*16 + lrow;
      float bv = bias[col];
      #pragma unroll
      for (int r=0;r<4;++r){
        size_t idx = (size_t)(rowb+r)*N + col;
        float vv = acc[mf][nf][r] + bv;
        if constexpr (EPI==3){ vv += ((const float*)res)[idx]; ((bf16*)Cp)[idx] = f2b(vv); }
        else { vv += b2f(((const bf16*)res)[idx]); ((float*)Cp)[idx] = vv; }
      }
    }
  }
}

// ---------------- flash attention v11: 3-slot ring, counted vmcnt, static softmax, in-reg P exchange ----------------
__global__ __launch_bounds__(512,6) void attn_k(const bf16* __restrict__ q, const bf16* __restrict__ k,
                                                const bf16* __restrict__ vT, bf16* __restrict__ o, int ldq){
  __shared__ char KV[3][16384];   // [slot][K 8KB | V 8KB]

  int flat = blockIdx.x;
  int xs = flat & 7, j = flat >> 3;
  int bh = xs*4 + (j & 3), qt = j >> 2;
  int b = bh >> 4, h = bh & 15;
  int t = threadIdx.x, lane = t & 63, w = t >> 6;
  int lrow = lane & 15, g = lane >> 4, lko = g*8;

  const bf16* kbase = k  + (size_t)b*2048*ldq + h*64;
  const bf16* vtb   = vT + (size_t)bh*64*2048;

  size_t qrow = (size_t)(b*2048 + qt*128 + w*16 + lrow);
  short8 qf0 = *(const short8*)(q + qrow*ldq + h*64 + lko);
  short8 qf1 = *(const short8*)(q + qrow*ldq + h*64 + 32 + lko);

  int srow = t >> 3, scolb = (t & 7) << 4;
  int ssw = scolb ^ ((srow & 7) << 4);
  const bf16* ksrc = kbase + (size_t)srow*ldq + (ssw >> 1);
  const bf16* vsrc = vtb   + (size_t)srow*2048 + (ssw >> 1);
  unsigned ldst = (unsigned)(w*1024);

  const short8 onesf = {0x3F80,0x3F80,0x3F80,0x3F80,0x3F80,0x3F80,0x3F80,0x3F80};

  const int srcU = lrow + ((2*(g&1) + (g>>1)) << 4);
  const int srcV = lrow + ((2*(g&1) + 1 - (g>>1)) << 4);
  const bool gOdd = (g & 1), lo = ((g>>1) == 0);

  f32x4 lacc = {};
  f32x4 oacc[4] = {};
  const int sw = (lrow & 7) << 4;

  auto STAGE = [&](int tile){
    char* s = KV[tile % 3];
    int kt = tile * 64;
    gload_lds16(ksrc + (size_t)kt*ldq, s + ldst);
    gload_lds16(vsrc + kt,             s + 8192 + ldst);
  };

  auto BODY = [&](int tile){
    const char* Kc = KV[tile % 3];
    const char* Vc = Kc + 8192;

    f32x4 s[4];
    __builtin_amdgcn_s_setprio(1);
    #pragma unroll
    for (int cb=0; cb<4; ++cb){
      const char* kp = Kc + (cb*16 + lrow)*128;
      short8 kf0 = *(const short8*)(kp + ((g*16) ^ sw));
      short8 kf1 = *(const short8*)(kp + ((64 + g*16) ^ sw));
      f32x4 a = {};
      a = __builtin_amdgcn_mfma_f32_16x16x32_bf16(kf0, qf0, a, 0,0,0);
      a = __builtin_amdgcn_mfma_f32_16x16x32_bf16(kf1, qf1, a, 0,0,0);
      s[cb] = a;
    }
    __builtin_amdgcn_s_setprio(0);

    unsigned pA0 = pk2(e2(s[0][0]), e2(s[0][1]));
    unsigned pB0 = pk2(e2(s[0][2]), e2(s[0][3]));
    unsigned pA1 = pk2(e2(s[1][0]), e2(s[1][1]));
    unsigned pB1 = pk2(e2(s[1][2]), e2(s[1][3]));
    unsigned pA2 = pk2(e2(s[2][0]), e2(s[2][1]));
    unsigned pB2 = pk2(e2(s[2][2]), e2(s[2][3]));
    unsigned pA3 = pk2(e2(s[3][0]), e2(s[3][1]));
    unsigned pB3 = pk2(e2(s[3][2]), e2(s[3][3]));

    unsigned ruA = __shfl((int)(gOdd?pA1:pA0), srcU, 64);
    unsigned rvA = __shfl((int)(gOdd?pA0:pA1), srcV, 64);
    unsigned ruB = __shfl((int)(gOdd?pB1:pB0), srcU, 64);
    unsigned rvB = __shfl((int)(gOdd?pB0:pB1), srcV, 64);
    unsigned ruA2= __shfl((int)(gOdd?pA3:pA2), srcU, 64);
    unsigned rvA2= __shfl((int)(gOdd?pA2:pA3), srcV, 64);
    unsigned ruB2= __shfl((int)(gOdd?pB3:pB2), srcU, 64);
    unsigned rvB2= __shfl((int)(gOdd?pB2:pB3), srcV, 64);

    u32x4 w0 = { lo?ruA:rvA,  lo?ruB:rvB,  lo?rvA:ruA,  lo?rvB:ruB  };
    u32x4 w1 = { lo?ruA2:rvA2,lo?ruB2:rvB2,lo?rvA2:ruA2,lo?rvB2:ruB2};
    short8 pf0 = __builtin_bit_cast(short8, w0);
    short8 pf1 = __builtin_bit_cast(short8, w1);

    __builtin_amdgcn_s_setprio(1);
    lacc = __builtin_amdgcn_mfma_f32_16x16x32_bf16(pf0, onesf, lacc, 0,0,0);
    lacc = __builtin_amdgcn_mfma_f32_16x16x32_bf16(pf1, onesf, lacc, 0,0,0);
    #pragma unroll
    for (int half=0; half<2; ++half){
      short8 pf = half ? pf1 : pf0;
      #pragma unroll
      for (int db=0; db<4; ++db){
        const char* vp = Vc + (db*16 + lrow)*128;
        short8 vf = *(const short8*)(vp + ((half*64 + g*16) ^ sw));
        oacc[db] = __builtin_amdgcn_mfma_f32_16x16x32_bf16(pf, vf, oacc[db], 0,0,0);
      }
    }
    __builtin_amdgcn_s_setprio(0);
  };

  STAGE(0); STAGE(1);
  asm volatile("s_waitcnt vmcnt(2)" ::: "memory");
  __builtin_amdgcn_s_barrier();

  for (int tile = 0; tile < 30; ++tile){
    STAGE(tile+2);
    BODY(tile);
    asm volatile("s_waitcnt vmcnt(2)" ::: "memory");
    __builtin_amdgcn_s_barrier();
  }
  BODY(30);
  asm volatile("s_waitcnt vmcnt(0)" ::: "memory");
  __builtin_amdgcn_s_barrier();
  BODY(31);

  f32x4 inv;
  #pragma unroll
  for (int r=0;r<4;++r) inv[r] = 1.0f/lacc[r];
  size_t obase = ((size_t)(b*2048 + qt*128 + w*16))*1024 + h*64;
  #pragma unroll
  for (int db=0; db<4; ++db)
    #pragma unroll
    for (int r=0;r<4;++r)
      o[obase + (size_t)(g*4+r)*1024 + db*16 + lrow] = f2b(oacc[db][r] * inv[r]);
}

// ---------------- launch ----------------
extern "C" void kernel_launch(void* const* d_in, const int* in_sizes, int n_in,
                              void* d_out, int out_size, void* d_ws, size_t ws_size,
                              hipStream_t stream) {
  (void)in_sizes; (void)n_in; (void)out_size; (void)ws_size;
  const float* x    = (const float*)d_in[0];
  const float* ln1w = (const float*)d_in[1];
  const float* ln1b = (const float*)d_in[2];
  const float* ln2w = (const float*)d_in[3];
  const float* ln2b = (const float*)d_in[4];
  const float* wq   = (const float*)d_in[5];
  const float* bq   = (const float*)d_in[6];
  const float* wk   = (const float*)d_in[7];
  const float* bk   = (const float*)d_in[8];
  const float* wv   = (const float*)d_in[9];
  const float* bv   = (const float*)d_in[10];
  const float* wo   = (const float*)d_in[11];
  const float* bo   = (const float*)d_in[12];
  const float* w1   = (const float*)d_in[13];
  const float* b1   = (const float*)d_in[14];
  const float* w2   = (const float*)d_in[15];
  const float* b2   = (const float*)d_in[16];

  char* ws = (char*)d_ws;
  const size_t MB = 1u<<20;
  bf16* wqkvT = (bf16*)(ws + 0*MB);   // [3072,1024] bf16
  bf16* woT   = (bf16*)(ws + 6*MB);
  bf16* w1T   = (bf16*)(ws + 8*MB);   // [4096,1024]
  bf16* w2T   = (bf16*)(ws + 16*MB);  // [1024,4096]
  bf16* qkv   = (bf16*)(ws + 24*MB);  // [4096,3072] bf16 (V third unused)
  bf16* ao    = (bf16*)(ws + 48*MB);  // [4096,1024] bf16 = 8 MB
  bf16* vT    = (bf16*)(ws + 56*MB);  // [2048,2048] bf16 = 8 MB, written by gemm256<0>
  bf16* x1b   = (bf16*)(ws + 64*MB);  // [4096,1024] bf16 residual = 8 MB
  bf16* lnb   = (bf16*)(ws + 72*MB);  // 8 MB
  bf16* h1    = (bf16*)(ws + 24*MB);  // [4096,4096] bf16 = 32 MB, reuse qkv+ao after proj
  float* bqkv = (float*)(ws + 80*MB); // 12 KB

  hipMemcpyAsync(bqkv,        bq, 1024*sizeof(float), hipMemcpyDeviceToDevice, stream);
  hipMemcpyAsync(bqkv + 1024, bk, 1024*sizeof(float), hipMemcpyDeviceToDevice, stream);
  hipMemcpyAsync(bqkv + 2048, bv, 1024*sizeof(float), hipMemcpyDeviceToDevice, stream);

  transpose_all<<<12288,256,0,stream>>>(wq, wk, wv, wo, w1, w2, wqkvT, woT, w1T, w2T);

  ln_f32<<<4096,256,0,stream>>>(x, ln1w, ln1b, lnb);
  gemm256<0><<<192,512,131072,stream>>>(lnb, wqkvT, bqkv, qkv, vT, 4096,3072,1024);
  attn_k<<<512,512,0,stream>>>(qkv, qkv + 1024, vT, ao, 3072);
  gemm128<3><<<256,512,131072,stream>>>(ao, woT, bo, x, x1b, 4096,1024,1024);
  ln_b16<<<4096,256,0,stream>>>(x1b, ln2w, ln2b, lnb);
  gemm256<1><<<256,512,131072,stream>>>(lnb, w1T, b1, h1, nullptr, 4096,4096,1024);
  gemm128<4><<<256,512,131072,stream>>>(h1, w2T, b2, x1b, (float*)d_out, 4096,1024,4096);
}